// Round 5
// baseline (229.313 us; speedup 1.0000x reference)
//
#include <hip/hip_runtime.h>
#include <hip/hip_bf16.h>

#define B_ 512
#define S_ 256
#define N_ 180
#define BSN_ ((long)B_*S_*N_)

typedef __attribute__((ext_vector_type(4))) float f32x4;
typedef __attribute__((ext_vector_type(8))) short s16x8;

static __device__ inline short f2bf(float f) {
  union { float f; unsigned u; } v; v.f = f;
  unsigned r = v.u + 0x7FFF + ((v.u >> 16) & 1);   // RNE
  return (short)(r >> 16);
}

// LDS-only barrier: does NOT drain vmcnt, so global stores stay in flight.
// (__syncthreads would emit s_waitcnt vmcnt(0) and serialize stores vs compute.)
static __device__ inline void lds_barrier() {
  asm volatile("s_waitcnt lgkmcnt(0)" ::: "memory");
  __builtin_amdgcn_s_barrier();
}

// One block per batch, 256 threads (4 waves), chunk = 16 timesteps.
// Phases per chunk: B(template scan + next-chunk load issue) |bar| C(MFMA +
// exp/stage next chunk) |bar| D(l4/adapt/l23). Global stores never drained.
__global__ __launch_bounds__(256, 2) void v1_fused(
    const int* __restrict__ ori, const float* __restrict__ logits,
    const float* __restrict__ plog, const float* __restrict__ narrow,
    const float* __restrict__ broad, float* __restrict__ out) {
  __shared__ float u[2][16*180];     // exp(logits), double-buffered
  __shared__ float tmplf[16*180];    // template rows, f32
  __shared__ float cmp[16*180];      // comparator rows, f32
  __shared__ short At[16*200];       // template rows bf16, padded K
  __shared__ float sc_l[2][16];      // 0.2*prec/rowsum
  __shared__ float precs[2][16];     // sigmoid(prec_logit)
  __shared__ int   ocache[2][16];

  int b = blockIdx.x;
  int tid = threadIdx.x;
  int w = tid >> 6, l = tid & 63;
  int lr = l & 15, lg = l >> 4;
  bool act = (tid < N_);
  bool seg2 = (l < N_ - 128);

  long base = (long)b * S_ * N_;
  const float* Lb = logits + base;
  const float* Pb = plog + (long)b * S_;
  const int*   Ob = ori + (long)b * S_;
  float* l4_out  = out + base;
  float* l23_out = out + 1*BSN_ + base;
  float* t_out   = out + 2*BSN_ + base;
  float* ad_out  = out + 3*BSN_ + base;
  float* cp_out  = out + 4*BSN_ + base;

  // zero-pad At cols 180..199 once
  for (int idx = tid; idx < 320; idx += 256) {
    int r = idx / 20, c = idx - r * 20;
    At[r * 200 + 180 + c] = 0;
  }

  // Persistent B-fragments of C = broad - 0.5*narrow (bf16), 72 VGPRs.
  s16x8 bf[3][6];
  #pragma unroll
  for (int i = 0; i < 3; ++i) {
    int c = (i * 4 + w) * 16 + lr;
    #pragma unroll
    for (int ks = 0; ks < 6; ++ks) {
      s16x8 v;
      #pragma unroll
      for (int j = 0; j < 8; ++j) {
        int k = ks * 32 + lg * 8 + j;
        float x = (k < N_ && c < N_) ? broad[k*N_ + c] - 0.5f*narrow[k*N_ + c] : 0.f;
        v[j] = f2bf(x);
      }
      bf[i][ks] = v;
    }
  }

  // Prologue: stage chunk 0 (4 rows per wave)
  {
    #pragma unroll
    for (int r = 0; r < 4; ++r) {
      int j = w * 4 + r;
      const float* rp = Lb + (long)j * N_;
      float e0 = __expf(rp[l]);
      float e1 = __expf(rp[l + 64]);
      float e2 = seg2 ? __expf(rp[l + 128]) : 0.f;
      float s = e0 + e1 + e2;
      #pragma unroll
      for (int o = 32; o; o >>= 1) s += __shfl_xor(s, o);
      u[0][j*180 + l] = e0;
      u[0][j*180 + l + 64] = e1;
      if (seg2) u[0][j*180 + l + 128] = e2;
      if (l == 0) {
        float pr = 1.f / (1.f + __expf(-Pb[j]));
        precs[0][j] = pr;
        sc_l[0][j] = 0.2f * pr / s;
      }
    }
    if (tid < 16) ocache[0][tid] = Ob[tid];
  }
  lds_barrier();

  float tcarry = 0.f, a = 0.f, l4v = 0.f, cl = 0.f;

  for (int c = 0; c < 16; ++c) {
    int pb = c & 1;
    int sc = c * 16;
    bool more = (c + 1 < 16);

    // ---- B: issue next-chunk loads early, then template scan ----
    float x0[4], x1[4], x2[4];
    if (more) {
      int nb = sc + 16;
      #pragma unroll
      for (int r = 0; r < 4; ++r) {
        const float* rp = Lb + (long)(nb + w*4 + r) * N_;
        x0[r] = rp[l];
        x1[r] = rp[l + 64];
        x2[r] = seg2 ? rp[l + 128] : 0.f;
      }
    }

    if (act) {
      #pragma unroll 4
      for (int j = 0; j < 16; ++j) {
        tcarry = 0.8f * tcarry + u[pb][j*180 + tid] * sc_l[pb][j];
        tmplf[j*180 + tid] = tcarry;
        At[j*200 + tid] = f2bf(tcarry);
        t_out[(long)(sc + j) * N_ + tid] = tcarry;
      }
    }
    lds_barrier();

    // ---- C: comparator MFMA, then exp/stage next chunk into u[qb] ----
    f32x4 acc[3];
    #pragma unroll
    for (int i = 0; i < 3; ++i) acc[i] = (f32x4)(0.f);
    #pragma unroll
    for (int ks = 0; ks < 6; ++ks) {
      s16x8 af = *(const s16x8*)(&At[lr*200 + ks*32 + lg*8]);
      #pragma unroll
      for (int i = 0; i < 3; ++i)
        acc[i] = __builtin_amdgcn_mfma_f32_16x16x32_bf16(af, bf[i][ks], acc[i], 0, 0, 0);
    }
    #pragma unroll
    for (int i = 0; i < 3; ++i) {
      int col = (i*4 + w)*16 + lr;
      if (col < N_) {
        #pragma unroll
        for (int r = 0; r < 4; ++r) {
          int row = lg*4 + r;
          float v = acc[i][r] * precs[pb][row];
          cp_out[(long)(sc + row)*N_ + col] = v;
          cmp[row*180 + col] = v;
        }
      }
    }

    if (more) {
      int nb = sc + 16;
      int qb = pb ^ 1;
      #pragma unroll
      for (int r = 0; r < 4; ++r) {
        int j = w*4 + r;
        float e0 = __expf(x0[r]);
        float e1 = __expf(x1[r]);
        float e2 = seg2 ? __expf(x2[r]) : 0.f;
        float s = e0 + e1 + e2;
        #pragma unroll
        for (int o = 32; o; o >>= 1) s += __shfl_xor(s, o);
        u[qb][j*180 + l] = e0;
        u[qb][j*180 + l + 64] = e1;
        if (seg2) u[qb][j*180 + l + 128] = e2;
        if (l == 0) {
          float pr = 1.f / (1.f + __expf(-Pb[nb + j]));
          precs[qb][j] = pr;
          sc_l[qb][j] = 0.2f * pr / s;
        }
      }
      if (tid < 16) ocache[qb][tid] = Ob[nb + tid];
    }
    lds_barrier();

    // ---- D: l4/adapt/l23 scan (threads 0..179), reduction-free ----
    // No barrier after D: tmplf reads are same-thread-exclusive, and all
    // cross-thread LDS hazards are covered by bar1(c+1)/bar2.
    if (act) {
      #pragma unroll 4
      for (int j = 0; j < 16; ++j) {
        int o = ocache[pb][j];
        a = 0.9f * a + 0.2f * l4v;
        float d = (tid == o) ? fmaxf(1.f - a, 0.f) : 0.f;
        l4v = d * __builtin_amdgcn_rcpf(1.f + d * (1.f/180.f));
        float tv = tmplf[j*180 + tid];
        float qv = cmp[j*180 + tid];
        cl = fmaxf(l4v + 0.5f * cl + tv - qv, 0.f);
        long p = (long)(sc + j)*N_ + tid;
        l4_out[p]  = l4v;
        l23_out[p] = cl;
        ad_out[p]  = a;
      }
    }
  }
}

extern "C" void kernel_launch(void* const* d_in, const int* in_sizes, int n_in,
                              void* d_out, int out_size, void* d_ws, size_t ws_size,
                              hipStream_t stream) {
  const int*   ori    = (const int*)d_in[0];
  const float* logits = (const float*)d_in[1];
  const float* plog   = (const float*)d_in[2];
  const float* narrow = (const float*)d_in[3];
  const float* broad  = (const float*)d_in[4];
  float* out = (float*)d_out;

  v1_fused<<<B_, 256, 0, stream>>>(ori, logits, plog, narrow, broad, out);
}

// Round 6
// 214.411 us; speedup vs baseline: 1.0695x; 1.0695x over previous
//
#include <hip/hip_runtime.h>
#include <hip/hip_bf16.h>

#define B_ 512
#define S_ 256
#define N_ 180
#define BS_ (B_*S_)            // 131072
#define BSN_ ((long)BS_*N_)    // 23592960
#define NCHUNK 16

typedef __attribute__((ext_vector_type(4))) float f32x4;
typedef __attribute__((ext_vector_type(8))) short s16x8;

static __device__ inline short f2bf(float f) {
  union { float f; unsigned u; } v; v.f = f;
  unsigned r = v.u + 0x7FFF + ((v.u >> 16) & 1);   // RNE
  return (short)(r >> 16);
}
static __device__ inline float bf2f(short h) {
  union { float f; unsigned u; } v; v.u = ((unsigned)(unsigned short)h) << 16;
  return v.f;
}
static __device__ inline void lds_barrier() {
  asm volatile("s_waitcnt lgkmcnt(0)" ::: "memory");
  __builtin_amdgcn_s_barrier();
}

// K0: cfrag (B-fragments of C = broad-0.5*narrow, bf16) + prec = sigmoid(plog)
__global__ void k0_prep(const float* __restrict__ narrow, const float* __restrict__ broad,
                        const float* __restrict__ plogit,
                        short* __restrict__ cfrag, float* __restrict__ prec) {
  int idx = blockIdx.x * 256 + threadIdx.x;
  if (idx < 12*6*64*8) {
    int j    = idx & 7;
    int lane = (idx >> 3) & 63;
    int g    = idx >> 9;
    int ks   = g % 6;
    int nt   = g / 6;
    int k = ks*32 + (lane >> 4)*8 + j;
    int c = nt*16 + (lane & 15);
    float v = 0.f;
    if (k < N_ && c < N_) v = broad[k*N_ + c] - 0.5f*narrow[k*N_ + c];
    cfrag[idx] = f2bf(v);
  }
  int p = idx - 12*6*64*8;
  if (p >= 0 && p < BS_) prec[p] = 1.f / (1.f + __expf(-plogit[p]));
}

// K1: scale[row] = 0.2*prec/sum(exp(logits_row)); one wave per row
__global__ void k1_scale(const float* __restrict__ logits, const float* __restrict__ prec,
                         float* __restrict__ scale) {
  int row = (blockIdx.x * 256 + threadIdx.x) >> 6;
  int l = threadIdx.x & 63;
  const float* rp = logits + (long)row * N_;
  float e0 = __expf(rp[l]);
  float e1 = __expf(rp[l + 64]);
  float e2 = (l < N_ - 128) ? __expf(rp[l + 128]) : 0.f;
  float s = e0 + e1 + e2;
  #pragma unroll
  for (int o = 32; o; o >>= 1) s += __shfl_xor(s, o);
  if (l == 0) scale[row] = 0.2f * prec[row] / s;
}

// K2: per-(b,n) strand scan emitting chunk-boundary checkpoints for
// template-carry, adaptation, l4. One block per batch, 192 threads.
__global__ __launch_bounds__(192) void k2_checkpoint(
    const float* __restrict__ logits, const int* __restrict__ ori,
    const float* __restrict__ scale,
    float* __restrict__ cp_t, float* __restrict__ cp_a, float* __restrict__ cp_l4) {
  __shared__ float sc_l[256];
  __shared__ int   o_l[256];
  int b = blockIdx.x, tid = threadIdx.x;
  for (int i = tid; i < 256; i += 192) {
    sc_l[i] = scale[b*S_ + i];
    o_l[i]  = ori[b*S_ + i];
  }
  lds_barrier();
  if (tid >= N_) return;
  int n = tid;
  const float* lp = logits + (long)b * S_ * N_ + n;
  long cpb = (long)b * N_ + n;
  cp_t[cpb] = 0.f; cp_a[cpb] = 0.f; cp_l4[cpb] = 0.f;   // chunk-0 state
  float t = 0.f, a = 0.f, l4 = 0.f;
  for (int sc = 0; sc < S_; sc += 16) {
    for (int jc = 0; jc < 16; jc += 8) {
      float xs[8];
      #pragma unroll
      for (int r = 0; r < 8; ++r) xs[r] = lp[(long)(sc + jc + r) * N_];
      #pragma unroll
      for (int r = 0; r < 8; ++r) {
        int s = sc + jc + r;
        t = 0.8f * t + __expf(xs[r]) * sc_l[s];
        a = 0.9f * a + 0.2f * l4;
        float d = (n == o_l[s]) ? fmaxf(1.f - a, 0.f) : 0.f;
        l4 = d * __builtin_amdgcn_rcpf(1.f + d * (1.f/180.f));
      }
    }
    int c = sc/16 + 1;
    if (c < NCHUNK) {
      long p = (long)c * B_ * N_ + cpb;
      cp_t[p] = t; cp_a[p] = a; cp_l4[p] = l4;
    }
  }
}

// K3: one block per (batch, chunk). WARM warm-up steps recomputed from exact
// checkpoints (template/l4/adapt); l23 starts cl=0 at s0 — 0.5^WARM decay
// makes the truncation < 1e-4. Writes the 16 real rows of all 5 outputs.
template<int WARM>
__global__ __launch_bounds__(256, 4) void k3_main(
    const int* __restrict__ ori, const float* __restrict__ logits,
    const float* __restrict__ scale, const float* __restrict__ prec,
    const float* __restrict__ cp_t, const float* __restrict__ cp_a,
    const float* __restrict__ cp_l4, const short* __restrict__ cfrag,
    float* __restrict__ out) {
  constexpr int NROW = WARM + 16;
  constexpr int MT = NROW / 16;
  __shared__ short At[NROW * 200];     // template rows bf16, padded K
  __shared__ float cmp[NROW * 180];    // comparator rows f32
  __shared__ float sc_l[NROW], pr_l[NROW];
  __shared__ int   o_l[NROW];

  int b = blockIdx.y;
  int c = WARM ? (blockIdx.x + 1) : 0;
  int s0 = c * 16 - WARM;
  int tid = threadIdx.x;
  int w = tid >> 6, l = tid & 63, lr = l & 15, lg = l >> 4;
  bool act = (tid < N_);
  int n = tid;

  if (tid < NROW) {
    int s = s0 + tid;
    sc_l[tid] = scale[b*S_ + s];
    pr_l[tid] = prec[b*S_ + s];
    o_l[tid]  = ori[b*S_ + s];
  }
  for (int i = tid; i < NROW * 20; i += 256) {   // zero-pad At cols 180..199
    int r = i / 20, q = i - r * 20;
    At[r * 200 + 180 + q] = 0;
  }
  lds_barrier();

  long cpidx = (long)(c - 1) * B_ * N_ + (long)b * N_;   // used only when WARM

  // ---- phase 1: template recursion (exact from checkpoint) ----
  if (act) {
    float t = WARM ? cp_t[cpidx + n] : 0.f;
    const float* lp = logits + ((long)b*S_ + s0) * N_ + n;
    float* tp = out + 2*BSN_ + ((long)b*S_ + s0) * N_ + n;
    for (int jc = 0; jc < NROW; jc += 8) {
      float xs[8];
      #pragma unroll
      for (int r = 0; r < 8; ++r) xs[r] = lp[(long)(jc + r) * N_];
      #pragma unroll
      for (int r = 0; r < 8; ++r) {
        int j = jc + r;
        t = 0.8f * t + __expf(xs[r]) * sc_l[j];
        At[j * 200 + n] = f2bf(t);
        if (j >= WARM) tp[(long)j * N_] = t;
      }
    }
  }
  lds_barrier();

  // ---- phase 2: comparator GEMM (template @ C) * prec ----
  {
    float* cp_out = out + 4*BSN_;
    for (int i = 0; i < 3; ++i) {
      int ntile = i * 4 + w;
      s16x8 bf[6];
      #pragma unroll
      for (int ks = 0; ks < 6; ++ks)
        bf[ks] = *(const s16x8*)(cfrag + ((ntile*6 + ks)*64 + l)*8);
      #pragma unroll
      for (int mt = 0; mt < MT; ++mt) {
        f32x4 acc = (f32x4)(0.f);
        #pragma unroll
        for (int ks = 0; ks < 6; ++ks) {
          s16x8 af = *(const s16x8*)(&At[(mt*16 + lr)*200 + ks*32 + lg*8]);
          acc = __builtin_amdgcn_mfma_f32_16x16x32_bf16(af, bf[ks], acc, 0, 0, 0);
        }
        int col = ntile * 16 + lr;
        if (col < N_) {
          #pragma unroll
          for (int r = 0; r < 4; ++r) {
            int row = mt*16 + lg*4 + r;
            float v = acc[r] * pr_l[row];
            cmp[row * 180 + col] = v;
            if (WARM == 0 || mt == MT - 1)
              cp_out[((long)b*S_ + s0 + row) * N_ + col] = v;
          }
        }
      }
    }
  }
  lds_barrier();

  // ---- phase 3: l4/adapt (exact from checkpoint) + l23 (contraction warm-up) ----
  if (act) {
    float a  = WARM ? cp_a [cpidx + n] : 0.f;
    float l4 = WARM ? cp_l4[cpidx + n] : 0.f;
    float cl = 0.f;
    float* l4p = out + ((long)b*S_ + s0) * N_ + n;
    float* clp = out + 1*BSN_ + ((long)b*S_ + s0) * N_ + n;
    float* adp = out + 3*BSN_ + ((long)b*S_ + s0) * N_ + n;
    for (int jc = 0; jc < NROW; jc += 8) {
      float tv[8], qv[8]; int ov[8];
      #pragma unroll
      for (int r = 0; r < 8; ++r) {
        int j = jc + r;
        tv[r] = bf2f(At[j * 200 + n]);
        qv[r] = cmp[j * 180 + n];
        ov[r] = o_l[j];
      }
      #pragma unroll
      for (int r = 0; r < 8; ++r) {
        int j = jc + r;
        a = 0.9f * a + 0.2f * l4;
        float d = (n == ov[r]) ? fmaxf(1.f - a, 0.f) : 0.f;
        l4 = d * __builtin_amdgcn_rcpf(1.f + d * (1.f/180.f));
        cl = fmaxf(l4 + 0.5f * cl + tv[r] - qv[r], 0.f);
        if (j >= WARM) {
          l4p[(long)j * N_] = l4;
          clp[(long)j * N_] = cl;
          adp[(long)j * N_] = a;
        }
      }
    }
  }
}

extern "C" void kernel_launch(void* const* d_in, const int* in_sizes, int n_in,
                              void* d_out, int out_size, void* d_ws, size_t ws_size,
                              hipStream_t stream) {
  const int*   ori    = (const int*)d_in[0];
  const float* logits = (const float*)d_in[1];
  const float* plog   = (const float*)d_in[2];
  const float* narrow = (const float*)d_in[3];
  const float* broad  = (const float*)d_in[4];
  float* out = (float*)d_out;

  // workspace layout (floats); ws is ~1.4 GB per the harness poison size
  float* ws    = (float*)d_ws;
  float* prec  = ws;                         // BS_
  float* scale = ws + BS_;                   // BS_
  float* cp_t  = ws + 2*BS_;                 // 16*512*180
  float* cp_a  = cp_t + (long)NCHUNK*B_*N_;
  float* cp_l4 = cp_a + (long)NCHUNK*B_*N_;
  short* cfrag = (short*)(cp_l4 + (long)NCHUNK*B_*N_);   // 12*6*64*8 bf16

  k0_prep<<<656, 256, 0, stream>>>(narrow, broad, plog, cfrag, prec);
  k1_scale<<<32768, 256, 0, stream>>>(logits, prec, scale);
  k2_checkpoint<<<B_, 192, 0, stream>>>(logits, ori, scale, cp_t, cp_a, cp_l4);
  k3_main<0><<<dim3(1, B_), 256, 0, stream>>>(ori, logits, scale, prec,
                                              cp_t, cp_a, cp_l4, cfrag, out);
  k3_main<16><<<dim3(NCHUNK-1, B_), 256, 0, stream>>>(ori, logits, scale, prec,
                                                      cp_t, cp_a, cp_l4, cfrag, out);
}